// Round 8
// baseline (238.835 us; speedup 1.0000x reference)
//
#include <hip/hip_runtime.h>

#define FEAT 512
#define F4   128          // float4 per row
#define NSEG 1024
#define CHUNK 256         // rows per block in sum/broadcast passes

typedef float f4_t __attribute__((ext_vector_type(4)));

// ---------------- K1: segment boundaries + zero sums ----------------
// starts[s] = first row index with seg_id >= s (seg ids sorted).
// Also zeroes the 2MB sums buffer (avoids rocclr fill node — round-2 lesson).
__global__ void bounds_zero_kernel(const int* __restrict__ seg,
                                   int* __restrict__ starts,
                                   float* __restrict__ sums, int total) {
    int i = blockIdx.x * blockDim.x + threadIdx.x;
    if (sums != nullptr && i < NSEG * FEAT / 2) {
        ((float2*)sums)[i] = make_float2(0.f, 0.f);
    }
    if (i >= total) return;
    int cur = seg[i];
    int prev = (i == 0) ? -1 : seg[i - 1];
    for (int s = prev + 1; s <= cur; ++s) starts[s] = i;
    if (i == total - 1) {
        for (int s = cur + 1; s <= NSEG; ++s) starts[s] = total;
    }
}

// ---------------- K2: chunk-balanced partial sums (read 512MB) ----------------
// Each block owns exactly CHUNK rows. 512 threads = 4 row-groups x 128
// f4-columns. x8-unrolled CACHED reads (experiment: NT dropped) -> register
// acc -> LDS combine -> rg0 flushes 4 scalar atomicAdds per segment.
__global__ __launch_bounds__(512) void chunk_sum_kernel(
        const float* __restrict__ batch,
        const int* __restrict__ seg,
        const int* __restrict__ starts,
        float* __restrict__ sums, int total) {
    const int tid  = threadIdx.x;
    const int lane = tid & (F4 - 1);   // f4 column 0..127
    const int rg   = tid >> 7;         // row-group 0..3
    const int r0   = blockIdx.x * CHUNK;
    if (r0 >= total) return;
    const int r1   = min(r0 + CHUNK, total);

    const int s0 = seg[r0];
    const int s1 = seg[r1 - 1];

    const f4_t* b4 = (const f4_t*)batch;
    __shared__ f4_t red[4][F4];

    for (int s = s0; s <= s1; ++s) {
        const int a = max(starts[s], r0);      // block-uniform
        const int b = min(starts[s + 1], r1);  // block-uniform
        if (a >= b) continue;                  // uniform skip (empty segment)

        f4_t a0 = (f4_t)(0.f);
        f4_t a1 = (f4_t)(0.f);
        int r = a + rg;
        for (; r + 28 < b; r += 32) {
            const f4_t* p = b4 + (size_t)r * F4 + lane;
            f4_t v0 = p[0 * 4 * F4];
            f4_t v1 = p[1 * 4 * F4];
            f4_t v2 = p[2 * 4 * F4];
            f4_t v3 = p[3 * 4 * F4];
            f4_t v4 = p[4 * 4 * F4];
            f4_t v5 = p[5 * 4 * F4];
            f4_t v6 = p[6 * 4 * F4];
            f4_t v7 = p[7 * 4 * F4];
            a0 += v0; a1 += v1;
            a0 += v2; a1 += v3;
            a0 += v4; a1 += v5;
            a0 += v6; a1 += v7;
        }
        for (; r < b; r += 4) {
            a0 += b4[(size_t)r * F4 + lane];
        }
        a0 += a1;

        red[rg][lane] = a0;
        __syncthreads();
        if (rg == 0) {
            f4_t t = red[0][lane] + red[1][lane] + red[2][lane] + red[3][lane];
            float* dst = sums + (size_t)s * FEAT + lane * 4;
            atomicAdd(dst + 0, t.x);
            atomicAdd(dst + 1, t.y);
            atomicAdd(dst + 2, t.z);
            atomicAdd(dst + 3, t.w);
        }
        __syncthreads();
    }
}

// ---------------- K3: chunk-balanced broadcast (write 512MB) ----------------
// Each block owns exactly CHUNK output rows. Segment mean hoisted to a
// register, then x8-unrolled CACHED streaming stores (experiment: NT dropped).
__global__ __launch_bounds__(256) void broadcast_chunk_kernel(
        const int* __restrict__ seg,
        const int* __restrict__ starts,
        const float* __restrict__ sums,
        float* __restrict__ out, int total) {
    const int tid  = threadIdx.x;
    const int lane = tid & (F4 - 1);   // f4 column 0..127
    const int rg   = tid >> 7;         // row-group 0..1
    const int r0   = blockIdx.x * CHUNK;
    if (r0 >= total) return;
    const int r1   = min(r0 + CHUNK, total);

    const int s0 = seg[r0];
    const int s1 = seg[r1 - 1];

    const f4_t* m4 = (const f4_t*)sums;
    f4_t* o4 = (f4_t*)out;

    for (int s = s0; s <= s1; ++s) {
        const int sa = starts[s];
        const int sb = starts[s + 1];
        const int a = max(sa, r0);
        const int b = min(sb, r1);
        if (a >= b) continue;
        const int count = sb - sa;
        const float inv = 1.0f / (float)(count > 0 ? count : 1);
        const f4_t mean = m4[(size_t)s * F4 + lane] * inv;
        int r = a + rg;
        for (; r + 14 < b; r += 16) {
            f4_t* q = o4 + (size_t)r * F4 + lane;
            q[0 * 2 * F4] = mean;
            q[1 * 2 * F4] = mean;
            q[2 * 2 * F4] = mean;
            q[3 * 2 * F4] = mean;
            q[4 * 2 * F4] = mean;
            q[5 * 2 * F4] = mean;
            q[6 * 2 * F4] = mean;
            q[7 * 2 * F4] = mean;
        }
        for (; r < b; r += 2) {
            o4[(size_t)r * F4 + lane] = mean;
        }
    }
}

// ---------------- Fallback: fused kernel (needs only ~4KB ws) ----------------
__global__ __launch_bounds__(512) void seg_mean_fused_kernel(
        const float* __restrict__ batch,
        const int* __restrict__ starts,
        float* __restrict__ out) {
    const int s      = blockIdx.x;
    const int tid    = threadIdx.x;
    const int lane_f = tid & (F4 - 1);
    const int rgrp   = tid >> 7;

    const int start = starts[s];
    const int end   = starts[s + 1];
    const int count = end - start;

    const f4_t* b4 = (const f4_t*)batch;
    f4_t a0 = (f4_t)(0.f);
    f4_t a1 = (f4_t)(0.f);

    int r = start + rgrp;
    for (; r + 28 < end; r += 32) {
        const f4_t* p = b4 + (size_t)r * F4 + lane_f;
        f4_t v0 = p[0 * 4 * F4];
        f4_t v1 = p[1 * 4 * F4];
        f4_t v2 = p[2 * 4 * F4];
        f4_t v3 = p[3 * 4 * F4];
        f4_t v4 = p[4 * 4 * F4];
        f4_t v5 = p[5 * 4 * F4];
        f4_t v6 = p[6 * 4 * F4];
        f4_t v7 = p[7 * 4 * F4];
        a0 += v0; a1 += v1;
        a0 += v2; a1 += v3;
        a0 += v4; a1 += v5;
        a0 += v6; a1 += v7;
    }
    for (; r < end; r += 4) {
        a0 += b4[(size_t)r * F4 + lane_f];
    }
    a0 += a1;

    __shared__ f4_t red[4][F4];
    red[rgrp][lane_f] = a0;
    __syncthreads();

    if (rgrp == 0) {
        f4_t p0 = red[0][lane_f];
        f4_t p1 = red[1][lane_f];
        f4_t p2 = red[2][lane_f];
        f4_t p3 = red[3][lane_f];
        const float inv = 1.0f / (float)(count > 0 ? count : 1);
        red[0][lane_f] = (p0 + p1 + p2 + p3) * inv;
    }
    __syncthreads();

    const f4_t mean = red[0][lane_f];
    f4_t* o4 = (f4_t*)out;

    r = start + rgrp;
    for (; r + 28 < end; r += 32) {
        f4_t* q = o4 + (size_t)r * F4 + lane_f;
        q[0 * 4 * F4] = mean;
        q[1 * 4 * F4] = mean;
        q[2 * 4 * F4] = mean;
        q[3 * 4 * F4] = mean;
        q[4 * 4 * F4] = mean;
        q[5 * 4 * F4] = mean;
        q[6 * 4 * F4] = mean;
        q[7 * 4 * F4] = mean;
    }
    for (; r < end; r += 4) {
        o4[(size_t)r * F4 + lane_f] = mean;
    }
}

extern "C" void kernel_launch(void* const* d_in, const int* in_sizes, int n_in,
                              void* d_out, int out_size, void* d_ws, size_t ws_size,
                              hipStream_t stream) {
    const float* batch = (const float*)d_in[0];
    const int*   seg   = (const int*)d_in[1];
    float*       out   = (float*)d_out;
    const int total    = in_sizes[1];

    // ws layout: [sums: 2MB][starts: (NSEG+1)*4]
    const size_t sums_bytes = (size_t)NSEG * FEAT * sizeof(float);
    const size_t need       = sums_bytes + (NSEG + 1) * sizeof(int);

    const int nblk256 = (total + 255) / 256;

    if (ws_size >= need) {
        float* sums   = (float*)d_ws;
        int*   starts = (int*)((char*)d_ws + sums_bytes);

        bounds_zero_kernel<<<nblk256, 256, 0, stream>>>(seg, starts, sums, total);
        const int nchunks = (total + CHUNK - 1) / CHUNK;
        chunk_sum_kernel<<<nchunks, 512, 0, stream>>>(batch, seg, starts, sums, total);
        broadcast_chunk_kernel<<<nchunks, 256, 0, stream>>>(seg, starts, sums, out, total);
    } else {
        int* starts = (int*)d_ws;
        bounds_zero_kernel<<<nblk256, 256, 0, stream>>>(seg, starts, nullptr, total);
        seg_mean_fused_kernel<<<NSEG, 512, 0, stream>>>(batch, starts, out);
    }
}

// Round 9
// 197.381 us; speedup vs baseline: 1.2100x; 1.2100x over previous
//
#include <hip/hip_runtime.h>

#define FEAT 512
#define F4   128          // float4 per row
#define NSEG 1024
#define CHUNK 256         // rows per block in sum/broadcast passes

typedef float f4_t __attribute__((ext_vector_type(4)));

// ---------------- K1: segment boundaries + zero sums ----------------
__global__ void bounds_zero_kernel(const int* __restrict__ seg,
                                   int* __restrict__ starts,
                                   float* __restrict__ sums, int total) {
    int i = blockIdx.x * blockDim.x + threadIdx.x;
    if (sums != nullptr && i < NSEG * FEAT / 2) {
        ((float2*)sums)[i] = make_float2(0.f, 0.f);
    }
    if (i >= total) return;
    int cur = seg[i];
    int prev = (i == 0) ? -1 : seg[i - 1];
    for (int s = prev + 1; s <= cur; ++s) starts[s] = i;
    if (i == total - 1) {
        for (int s = cur + 1; s <= NSEG; ++s) starts[s] = total;
    }
}

// ---------------- K2: chunk-balanced partial sums (read 512MB, NT) ------------
// Each block owns exactly CHUNK rows. 512 threads = 4 row-groups x 128
// f4-columns. SOFTWARE-PIPELINED x8 NT reads: iteration i+1's loads are
// issued before iteration i's accumulate -> up to 16 loads in flight,
// vmcnt never drains to 0 in steady state (T4 principle).
__global__ __launch_bounds__(512) void chunk_sum_kernel(
        const float* __restrict__ batch,
        const int* __restrict__ seg,
        const int* __restrict__ starts,
        float* __restrict__ sums, int total) {
    const int tid  = threadIdx.x;
    const int lane = tid & (F4 - 1);   // f4 column 0..127
    const int rg   = tid >> 7;         // row-group 0..3
    const int r0   = blockIdx.x * CHUNK;
    if (r0 >= total) return;
    const int r1   = min(r0 + CHUNK, total);

    const int s0 = seg[r0];
    const int s1 = seg[r1 - 1];

    const f4_t* b4 = (const f4_t*)batch;
    __shared__ f4_t red[4][F4];

    for (int s = s0; s <= s1; ++s) {
        const int a = max(starts[s], r0);      // block-uniform
        const int b = min(starts[s + 1], r1);  // block-uniform
        if (a >= b) continue;                  // uniform skip (empty segment)

        f4_t a0 = (f4_t)(0.f);
        f4_t a1 = (f4_t)(0.f);
        int r = a + rg;

        if (r + 28 < b) {
            // prologue: load first batch of 8
            const f4_t* p = b4 + (size_t)r * F4 + lane;
            f4_t c0 = __builtin_nontemporal_load(p + 0 * 4 * F4);
            f4_t c1 = __builtin_nontemporal_load(p + 1 * 4 * F4);
            f4_t c2 = __builtin_nontemporal_load(p + 2 * 4 * F4);
            f4_t c3 = __builtin_nontemporal_load(p + 3 * 4 * F4);
            f4_t c4 = __builtin_nontemporal_load(p + 4 * 4 * F4);
            f4_t c5 = __builtin_nontemporal_load(p + 5 * 4 * F4);
            f4_t c6 = __builtin_nontemporal_load(p + 6 * 4 * F4);
            f4_t c7 = __builtin_nontemporal_load(p + 7 * 4 * F4);
            r += 32;
            // steady state: issue next 8 BEFORE accumulating current 8
            for (; r + 28 < b; r += 32) {
                const f4_t* q = b4 + (size_t)r * F4 + lane;
                f4_t n0 = __builtin_nontemporal_load(q + 0 * 4 * F4);
                f4_t n1 = __builtin_nontemporal_load(q + 1 * 4 * F4);
                f4_t n2 = __builtin_nontemporal_load(q + 2 * 4 * F4);
                f4_t n3 = __builtin_nontemporal_load(q + 3 * 4 * F4);
                f4_t n4 = __builtin_nontemporal_load(q + 4 * 4 * F4);
                f4_t n5 = __builtin_nontemporal_load(q + 5 * 4 * F4);
                f4_t n6 = __builtin_nontemporal_load(q + 6 * 4 * F4);
                f4_t n7 = __builtin_nontemporal_load(q + 7 * 4 * F4);
                a0 += c0; a1 += c1;
                a0 += c2; a1 += c3;
                a0 += c4; a1 += c5;
                a0 += c6; a1 += c7;
                c0 = n0; c1 = n1; c2 = n2; c3 = n3;
                c4 = n4; c5 = n5; c6 = n6; c7 = n7;
            }
            // epilogue: accumulate last batch
            a0 += c0; a1 += c1;
            a0 += c2; a1 += c3;
            a0 += c4; a1 += c5;
            a0 += c6; a1 += c7;
        }
        for (; r < b; r += 4) {
            a0 += __builtin_nontemporal_load(b4 + (size_t)r * F4 + lane);
        }
        a0 += a1;

        red[rg][lane] = a0;
        __syncthreads();
        if (rg == 0) {
            f4_t t = red[0][lane] + red[1][lane] + red[2][lane] + red[3][lane];
            float* dst = sums + (size_t)s * FEAT + lane * 4;
            atomicAdd(dst + 0, t.x);
            atomicAdd(dst + 1, t.y);
            atomicAdd(dst + 2, t.z);
            atomicAdd(dst + 3, t.w);
        }
        __syncthreads();
    }
}

// ---------------- K3: chunk-balanced broadcast (write 512MB, NT) --------------
__global__ __launch_bounds__(256) void broadcast_chunk_kernel(
        const int* __restrict__ seg,
        const int* __restrict__ starts,
        const float* __restrict__ sums,
        float* __restrict__ out, int total) {
    const int tid  = threadIdx.x;
    const int lane = tid & (F4 - 1);   // f4 column 0..127
    const int rg   = tid >> 7;         // row-group 0..1
    const int r0   = blockIdx.x * CHUNK;
    if (r0 >= total) return;
    const int r1   = min(r0 + CHUNK, total);

    const int s0 = seg[r0];
    const int s1 = seg[r1 - 1];

    const f4_t* m4 = (const f4_t*)sums;
    f4_t* o4 = (f4_t*)out;

    for (int s = s0; s <= s1; ++s) {
        const int sa = starts[s];
        const int sb = starts[s + 1];
        const int a = max(sa, r0);
        const int b = min(sb, r1);
        if (a >= b) continue;
        const int count = sb - sa;
        const float inv = 1.0f / (float)(count > 0 ? count : 1);
        const f4_t mean = m4[(size_t)s * F4 + lane] * inv;
        int r = a + rg;
        for (; r + 14 < b; r += 16) {
            f4_t* q = o4 + (size_t)r * F4 + lane;
            __builtin_nontemporal_store(mean, q + 0 * 2 * F4);
            __builtin_nontemporal_store(mean, q + 1 * 2 * F4);
            __builtin_nontemporal_store(mean, q + 2 * 2 * F4);
            __builtin_nontemporal_store(mean, q + 3 * 2 * F4);
            __builtin_nontemporal_store(mean, q + 4 * 2 * F4);
            __builtin_nontemporal_store(mean, q + 5 * 2 * F4);
            __builtin_nontemporal_store(mean, q + 6 * 2 * F4);
            __builtin_nontemporal_store(mean, q + 7 * 2 * F4);
        }
        for (; r < b; r += 2) {
            __builtin_nontemporal_store(mean, o4 + (size_t)r * F4 + lane);
        }
    }
}

// ---------------- Fallback: R5 fused kernel (needs only ~4KB ws) --------------
__global__ __launch_bounds__(512) void seg_mean_fused_kernel(
        const float* __restrict__ batch,
        const int* __restrict__ starts,
        float* __restrict__ out) {
    const int s      = blockIdx.x;
    const int tid    = threadIdx.x;
    const int lane_f = tid & (F4 - 1);
    const int rgrp   = tid >> 7;

    const int start = starts[s];
    const int end   = starts[s + 1];
    const int count = end - start;

    const f4_t* b4 = (const f4_t*)batch;
    f4_t a0 = (f4_t)(0.f);
    f4_t a1 = (f4_t)(0.f);

    int r = start + rgrp;
    for (; r + 28 < end; r += 32) {
        const f4_t* p = b4 + (size_t)r * F4 + lane_f;
        f4_t v0 = __builtin_nontemporal_load(p + 0 * 4 * F4);
        f4_t v1 = __builtin_nontemporal_load(p + 1 * 4 * F4);
        f4_t v2 = __builtin_nontemporal_load(p + 2 * 4 * F4);
        f4_t v3 = __builtin_nontemporal_load(p + 3 * 4 * F4);
        f4_t v4 = __builtin_nontemporal_load(p + 4 * 4 * F4);
        f4_t v5 = __builtin_nontemporal_load(p + 5 * 4 * F4);
        f4_t v6 = __builtin_nontemporal_load(p + 6 * 4 * F4);
        f4_t v7 = __builtin_nontemporal_load(p + 7 * 4 * F4);
        a0 += v0; a1 += v1;
        a0 += v2; a1 += v3;
        a0 += v4; a1 += v5;
        a0 += v6; a1 += v7;
    }
    for (; r < end; r += 4) {
        a0 += __builtin_nontemporal_load(b4 + (size_t)r * F4 + lane_f);
    }
    a0 += a1;

    __shared__ f4_t red[4][F4];
    red[rgrp][lane_f] = a0;
    __syncthreads();

    if (rgrp == 0) {
        f4_t p0 = red[0][lane_f];
        f4_t p1 = red[1][lane_f];
        f4_t p2 = red[2][lane_f];
        f4_t p3 = red[3][lane_f];
        const float inv = 1.0f / (float)(count > 0 ? count : 1);
        red[0][lane_f] = (p0 + p1 + p2 + p3) * inv;
    }
    __syncthreads();

    const f4_t mean = red[0][lane_f];
    f4_t* o4 = (f4_t*)out;

    r = start + rgrp;
    for (; r + 28 < end; r += 32) {
        f4_t* q = o4 + (size_t)r * F4 + lane_f;
        __builtin_nontemporal_store(mean, q + 0 * 4 * F4);
        __builtin_nontemporal_store(mean, q + 1 * 4 * F4);
        __builtin_nontemporal_store(mean, q + 2 * 4 * F4);
        __builtin_nontemporal_store(mean, q + 3 * 4 * F4);
        __builtin_nontemporal_store(mean, q + 4 * 4 * F4);
        __builtin_nontemporal_store(mean, q + 5 * 4 * F4);
        __builtin_nontemporal_store(mean, q + 6 * 4 * F4);
        __builtin_nontemporal_store(mean, q + 7 * 4 * F4);
    }
    for (; r < end; r += 4) {
        __builtin_nontemporal_store(mean, o4 + (size_t)r * F4 + lane_f);
    }
}

extern "C" void kernel_launch(void* const* d_in, const int* in_sizes, int n_in,
                              void* d_out, int out_size, void* d_ws, size_t ws_size,
                              hipStream_t stream) {
    const float* batch = (const float*)d_in[0];
    const int*   seg   = (const int*)d_in[1];
    float*       out   = (float*)d_out;
    const int total    = in_sizes[1];

    // ws layout: [sums: 2MB][starts: (NSEG+1)*4]
    const size_t sums_bytes = (size_t)NSEG * FEAT * sizeof(float);
    const size_t need       = sums_bytes + (NSEG + 1) * sizeof(int);

    const int nblk256 = (total + 255) / 256;

    if (ws_size >= need) {
        float* sums   = (float*)d_ws;
        int*   starts = (int*)((char*)d_ws + sums_bytes);

        bounds_zero_kernel<<<nblk256, 256, 0, stream>>>(seg, starts, sums, total);
        const int nchunks = (total + CHUNK - 1) / CHUNK;
        chunk_sum_kernel<<<nchunks, 512, 0, stream>>>(batch, seg, starts, sums, total);
        broadcast_chunk_kernel<<<nchunks, 256, 0, stream>>>(seg, starts, sums, out, total);
    } else {
        int* starts = (int*)d_ws;
        bounds_zero_kernel<<<nblk256, 256, 0, stream>>>(seg, starts, nullptr, total);
        seg_mean_fused_kernel<<<NSEG, 512, 0, stream>>>(batch, starts, out);
    }
}